// Round 1
// baseline (76.946 us; speedup 1.0000x reference)
//
#include <hip/hip_runtime.h>
#include <hip/hip_bf16.h>

#define DDIM 256   // feature dim (K)

typedef __bf16 bf16x8 __attribute__((ext_vector_type(8)));
typedef float  f32x4  __attribute__((ext_vector_type(4)));

// round-to-nearest-even f32 -> bf16 bits
__device__ __forceinline__ unsigned short f2bf(float f) {
  unsigned int u = __float_as_uint(f);
  unsigned int r = (u + 0x7fffu + ((u >> 16) & 1u)) >> 16;
  return (unsigned short)r;
}

// Per row: inv norms, exact f32 diagonal score, bf16 casts, zero row_sum.
__global__ __launch_bounds__(256) void prep_kernel(
    const float* __restrict__ q, const float* __restrict__ r,
    unsigned short* __restrict__ qbf, unsigned short* __restrict__ rbf,
    float* __restrict__ inv_q, float* __restrict__ inv_r,
    float* __restrict__ pos, float* __restrict__ row_sum) {
  int i = blockIdx.x;
  int t = threadIdx.x;
  int lane = t & 63, wave = t >> 6;
  float qv = q[(size_t)i * DDIM + t];
  float rv = r[(size_t)i * DDIM + t];
  qbf[(size_t)i * DDIM + t] = f2bf(qv);
  rbf[(size_t)i * DDIM + t] = f2bf(rv);
  float qq = qv * qv, rr = rv * rv, qr = qv * rv;
  #pragma unroll
  for (int m = 1; m < 64; m <<= 1) {
    qq += __shfl_xor(qq, m);
    rr += __shfl_xor(rr, m);
    qr += __shfl_xor(qr, m);
  }
  __shared__ float sq[4], sr[4], sx[4];
  if (lane == 0) { sq[wave] = qq; sr[wave] = rr; sx[wave] = qr; }
  __syncthreads();
  if (t == 0) {
    float QQ = sq[0] + sq[1] + sq[2] + sq[3];
    float RR = sr[0] + sr[1] + sr[2] + sr[3];
    float QR = sx[0] + sx[1] + sx[2] + sx[3];
    float qn = sqrtf(QQ), rn = sqrtf(RR);
    float iq = 1.0f / qn;   // norms ~16 for 256-dim normal data; eps clamp unreachable
    float ir = 1.0f / rn;
    inv_q[i] = iq;
    inv_r[i] = ir;
    pos[i] = QR * iq * ir;
    row_sum[i] = 0.0f;
  }
}

// Fused GEMM (Q @ R^T) + exp + row-sum. 128x128 tile, full K=256 in LDS.
// LDS layout: row-major [128][512B] with XOR swizzle on byte bits [6:4]:
// stored byte = row*512 + (inner ^ ((row&7)<<4)). global_load_lds writes
// linearly, so the SOURCE address is inverse-swizzled (rule 21).
__global__ __launch_bounds__(256) void gemm_lse_kernel(
    const unsigned short* __restrict__ qbf, const unsigned short* __restrict__ rbf,
    const float* __restrict__ inv_q, const float* __restrict__ inv_r,
    float* __restrict__ row_sum, int tiles_per_chunk) {
  __shared__ __attribute__((aligned(16))) unsigned short Alds[128 * DDIM]; // 64 KB
  __shared__ __attribute__((aligned(16))) unsigned short Blds[128 * DDIM]; // 64 KB

  const int tid  = threadIdx.x;
  const int lane = tid & 63;
  const int wave = tid >> 6;
  const int wr = wave >> 1, wc = wave & 1;     // 2x2 wave grid, each owns 64x64
  const int row0   = blockIdx.x * 128;
  const int chunk0 = blockIdx.y * tiles_per_chunk * 128;

  // ---- stage A tile (64 KB) once, async ----
  {
    char* g = (char*)qbf + (size_t)row0 * 512;
    #pragma unroll
    for (int it = 0; it < 16; ++it) {
      int cb    = wave * 1024 + it * 64;       // wave-uniform chunk base
      int chunk = cb + lane;
      int rowl  = chunk >> 5;                  // 32 chunks of 16B per 512B row
      int inner = (chunk & 31) << 4;
      int src   = rowl * 512 + (inner ^ ((rowl & 7) << 4));
      __builtin_amdgcn_global_load_lds(
          (__attribute__((address_space(1))) void*)(g + src),
          (__attribute__((address_space(3))) void*)((char*)Alds + cb * 16),
          16, 0, 0);
    }
  }

  // per-lane inv_q for the 16 output rows this lane owns (C layout:
  // col=lane&15, row=(lane>>4)*4+reg)
  float invq[16];
  #pragma unroll
  for (int m = 0; m < 4; ++m)
    #pragma unroll
    for (int g2 = 0; g2 < 4; ++g2)
      invq[m * 4 + g2] = inv_q[row0 + wr * 64 + m * 16 + (lane >> 4) * 4 + g2];

  float rs[16];
  #pragma unroll
  for (int k = 0; k < 16; ++k) rs[k] = 0.0f;

  for (int t = 0; t < tiles_per_chunk; ++t) {
    int col0 = chunk0 + t * 128;
    __syncthreads();  // prior tile's LDS reads done before overwriting B
    {
      char* g = (char*)rbf + (size_t)col0 * 512;
      #pragma unroll
      for (int it = 0; it < 16; ++it) {
        int cb    = wave * 1024 + it * 64;
        int chunk = cb + lane;
        int rowl  = chunk >> 5;
        int inner = (chunk & 31) << 4;
        int src   = rowl * 512 + (inner ^ ((rowl & 7) << 4));
        __builtin_amdgcn_global_load_lds(
            (__attribute__((address_space(1))) void*)(g + src),
            (__attribute__((address_space(3))) void*)((char*)Blds + cb * 16),
            16, 0, 0);
      }
    }
    __syncthreads();  // drains vmcnt: A (iter 0) and B tile are resident

    f32x4 acc[4][4];
    const f32x4 zero = {0.f, 0.f, 0.f, 0.f};
    #pragma unroll
    for (int m = 0; m < 4; ++m)
      #pragma unroll
      for (int nn = 0; nn < 4; ++nn) acc[m][nn] = zero;

    const char* Ab = (const char*)Alds;
    const char* Bb = (const char*)Blds;
    #pragma unroll
    for (int ks = 0; ks < 8; ++ks) {          // K = 8 x 32
      int kin = ks * 64 + (lane >> 4) * 16;   // byte offset of this lane's 8 bf16
      bf16x8 av[4], bv[4];
      #pragma unroll
      for (int m = 0; m < 4; ++m) {
        int rowl = wr * 64 + m * 16 + (lane & 15);
        av[m] = *(const bf16x8*)(Ab + rowl * 512 + (kin ^ ((rowl & 7) << 4)));
      }
      #pragma unroll
      for (int nn = 0; nn < 4; ++nn) {
        int coll = wc * 64 + nn * 16 + (lane & 15);
        bv[nn] = *(const bf16x8*)(Bb + coll * 512 + (kin ^ ((coll & 7) << 4)));
      }
      #pragma unroll
      for (int m = 0; m < 4; ++m)
        #pragma unroll
        for (int nn = 0; nn < 4; ++nn)
          acc[m][nn] = __builtin_amdgcn_mfma_f32_16x16x32_bf16(av[m], bv[nn],
                                                               acc[m][nn], 0, 0, 0);
    }

    // epilogue: score = dot * invq * invr; accumulate exp into per-row partials
    #pragma unroll
    for (int nn = 0; nn < 4; ++nn) {
      float ir = inv_r[col0 + wc * 64 + nn * 16 + (lane & 15)];
      #pragma unroll
      for (int m = 0; m < 4; ++m) {
        #pragma unroll
        for (int g2 = 0; g2 < 4; ++g2) {
          float s = acc[m][nn][g2] * invq[m * 4 + g2] * ir;
          rs[m * 4 + g2] += __expf(s);
        }
      }
    }
  }

  // reduce the 16 column-lanes (lane&15) holding the same row, then one atomic
  #pragma unroll
  for (int k = 0; k < 16; ++k) {
    float v = rs[k];
    v += __shfl_xor(v, 1);
    v += __shfl_xor(v, 2);
    v += __shfl_xor(v, 4);
    v += __shfl_xor(v, 8);
    if ((lane & 15) == 0) {
      int row = row0 + wr * 64 + (k >> 2) * 16 + (lane >> 4) * 4 + (k & 3);
      atomicAdd(&row_sum[row], v);
    }
  }
}

__global__ __launch_bounds__(256) void finalize_kernel(
    const float* __restrict__ row_sum, const float* __restrict__ pos,
    float* __restrict__ out, int n) {
  int t = threadIdx.x;
  float s = 0.f;
  for (int i = t; i < n; i += 256) s += __logf(row_sum[i]) - pos[i];
  #pragma unroll
  for (int m = 1; m < 64; m <<= 1) s += __shfl_xor(s, m);
  __shared__ float red[4];
  if ((t & 63) == 0) red[t >> 6] = s;
  __syncthreads();
  if (t == 0) out[0] = red[0] + red[1] + red[2] + red[3];  // -loss = sum(lse - pos)
}

extern "C" void kernel_launch(void* const* d_in, const int* in_sizes, int n_in,
                              void* d_out, int out_size, void* d_ws, size_t ws_size,
                              hipStream_t stream) {
  const float* q = (const float*)d_in[0];
  const float* r = (const float*)d_in[1];
  int n = in_sizes[0] / DDIM;  // 8192

  char* w = (char*)d_ws;
  size_t bfBytes = (size_t)n * DDIM * 2;
  unsigned short* qbf = (unsigned short*)w;
  unsigned short* rbf = (unsigned short*)(w + bfBytes);
  float* inv_q   = (float*)(w + 2 * bfBytes);
  float* inv_r   = inv_q + n;
  float* pos     = inv_r + n;
  float* row_sum = pos + n;

  prep_kernel<<<n, 256, 0, stream>>>(q, r, qbf, rbf, inv_q, inv_r, pos, row_sum);

  int row_tiles = n / 128;                  // 64
  int chunks = 4;                           // 64*4 = 256 blocks = 1 per CU
  int tiles_per_chunk = row_tiles / chunks; // 16
  dim3 grid(row_tiles, chunks);
  gemm_lse_kernel<<<grid, 256, 0, stream>>>(qbf, rbf, inv_q, inv_r, row_sum,
                                            tiles_per_chunk);

  finalize_kernel<<<1, 256, 0, stream>>>(row_sum, pos, (float*)d_out, n);
}

// Round 2
// 58.436 us; speedup vs baseline: 1.3168x; 1.3168x over previous
//
#include <hip/hip_runtime.h>
#include <hip/hip_bf16.h>

#define DDIM   256   // K (feature dim)
#define BROWS  128   // block output rows
#define BCOLS   32   // B tile columns
#define NTILES  16   // B tiles per block  -> 512 cols per chunk

typedef __bf16 bf16x8 __attribute__((ext_vector_type(8)));
typedef float  f32x4  __attribute__((ext_vector_type(4)));

// round-to-nearest-even f32 -> bf16 bits
__device__ __forceinline__ unsigned short f2bf(float f) {
  unsigned int u = __float_as_uint(f);
  return (unsigned short)((u + 0x7fffu + ((u >> 16) & 1u)) >> 16);
}

// ---- prep: one wave per row, lane handles 4 floats --------------------------
__global__ __launch_bounds__(256) void prep_kernel(
    const float* __restrict__ q, const float* __restrict__ r,
    unsigned short* __restrict__ qbf, unsigned short* __restrict__ rbf,
    float* __restrict__ inv_q, float* __restrict__ inv_r,
    float* __restrict__ pos, float* __restrict__ row_sum) {
  int lane = threadIdx.x & 63, wave = threadIdx.x >> 6;
  int row = blockIdx.x * 4 + wave;
  size_t base = (size_t)row * DDIM + lane * 4;
  float4 qv = *(const float4*)(q + base);
  float4 rv = *(const float4*)(r + base);
  ushort4 qs  = { f2bf(qv.x), f2bf(qv.y), f2bf(qv.z), f2bf(qv.w) };
  ushort4 rs4 = { f2bf(rv.x), f2bf(rv.y), f2bf(rv.z), f2bf(rv.w) };
  *(ushort4*)(qbf + base) = qs;
  *(ushort4*)(rbf + base) = rs4;
  float qq = qv.x*qv.x + qv.y*qv.y + qv.z*qv.z + qv.w*qv.w;
  float rr = rv.x*rv.x + rv.y*rv.y + rv.z*rv.z + rv.w*rv.w;
  float qr = qv.x*rv.x + qv.y*rv.y + qv.z*rv.z + qv.w*rv.w;
  #pragma unroll
  for (int m = 1; m < 64; m <<= 1) {
    qq += __shfl_xor(qq, m);
    rr += __shfl_xor(rr, m);
    qr += __shfl_xor(qr, m);
  }
  if (lane == 0) {
    float iq = 1.0f / sqrtf(qq);
    float ir = 1.0f / sqrtf(rr);
    inv_q[row] = iq;
    inv_r[row] = ir;
    pos[row] = qr * iq * ir;   // exact f32 diagonal
    row_sum[row] = 0.0f;
  }
}

// stage one 32-col x 256-K bf16 B tile (16 KB) into LDS, async, swizzled.
// LDS logical layout: byte(col, inner) = col*512 + (inner ^ ((col&7)<<4)).
// global_load_lds writes linearly (base + lane*16), so the swizzle is applied
// to the SOURCE address (rule 21: inverse-swz source + swz read).
__device__ __forceinline__ void stage_tile(unsigned short* dst,
                                           const unsigned short* src_base,
                                           int col0, int wid, int lane) {
  const char* gb = (const char*)src_base + (size_t)col0 * 512;
  #pragma unroll
  for (int it = 0; it < 4; ++it) {
    int cb = wid * 256 + it * 64;        // wave-uniform chunk base (16B units)
    int chunk = cb + lane;               // 0..1023
    int cc = chunk >> 5;                 // tile-local col 0..31
    int inner = (chunk & 31) << 4;       // byte offset within 512B row
    int off = cc * 512 + (inner ^ ((cc & 7) << 4));
    __builtin_amdgcn_global_load_lds(
        (const __attribute__((address_space(1))) void*)(gb + off),
        (__attribute__((address_space(3))) void*)((char*)dst + cb * 16),
        16, 0, 0);
  }
}

// compute one 128x32 tile: 8 K-steps of MFMA (A from registers, B from LDS),
// then exp-epilogue into per-row partial sums.
__device__ __forceinline__ void compute_tile(
    const unsigned short* Bt, const float* __restrict__ inv_r, int col0,
    const bf16x8 (&av)[2][8], const float (&invq)[8], float (&rs)[8],
    int g, int c) {
  const char* Bb = (const char*)Bt;
  float ir0 = inv_r[col0 + c];
  float ir1 = inv_r[col0 + 16 + c];
  f32x4 acc[2][2];
  const f32x4 zero = {0.f, 0.f, 0.f, 0.f};
  #pragma unroll
  for (int m = 0; m < 2; ++m)
    #pragma unroll
    for (int nn = 0; nn < 2; ++nn) acc[m][nn] = zero;

  #pragma unroll
  for (int ks = 0; ks < 8; ++ks) {
    int kin = ks * 64 + g * 16;
    int c1 = 16 + c;
    bf16x8 bv0 = *(const bf16x8*)(Bb + (size_t)c  * 512 + (kin ^ ((c  & 7) << 4)));
    bf16x8 bv1 = *(const bf16x8*)(Bb + (size_t)c1 * 512 + (kin ^ ((c1 & 7) << 4)));
    #pragma unroll
    for (int m = 0; m < 2; ++m) {
      acc[m][0] = __builtin_amdgcn_mfma_f32_16x16x32_bf16(av[m][ks], bv0, acc[m][0], 0, 0, 0);
      acc[m][1] = __builtin_amdgcn_mfma_f32_16x16x32_bf16(av[m][ks], bv1, acc[m][1], 0, 0, 0);
    }
  }

  // C layout (validated r1): col = nn*16 + (lane&15), row = m*16 + g*4 + j
  #pragma unroll
  for (int m = 0; m < 2; ++m)
    #pragma unroll
    for (int j = 0; j < 4; ++j) {
      float cf = invq[m * 4 + j];
      rs[m * 4 + j] += __expf(acc[m][0][j] * cf * ir0)
                     + __expf(acc[m][1][j] * cf * ir1);
    }
}

__global__ __launch_bounds__(256) void gemm_lse_kernel(
    const unsigned short* __restrict__ qbf, const unsigned short* __restrict__ rbf,
    const float* __restrict__ inv_q, const float* __restrict__ inv_r,
    float* __restrict__ row_sum) {
  __shared__ __attribute__((aligned(16))) unsigned short Bl[2][BCOLS * DDIM]; // 2 x 16 KB

  const int tid  = threadIdx.x;
  const int lane = tid & 63;
  const int wid  = tid >> 6;            // 4 waves, each owns 32 rows
  const int g = lane >> 4, c = lane & 15;
  const int row0  = blockIdx.x * BROWS;
  const int col00 = blockIdx.y * (NTILES * BCOLS);

  // issue stage of tile 0 first; its latency hides under the A-register loads
  stage_tile(&Bl[0][0], rbf, col00, wid, lane);

  // A fragments -> registers (2 row-frags x 8 K-slices, 64 VGPR), read once
  bf16x8 av[2][8];
  const char* Ab = (const char*)qbf;
  #pragma unroll
  for (int m = 0; m < 2; ++m) {
    size_t rb = (size_t)(row0 + wid * 32 + m * 16 + c) * 512;
    #pragma unroll
    for (int ks = 0; ks < 8; ++ks)
      av[m][ks] = *(const bf16x8*)(Ab + rb + ks * 64 + g * 16);
  }

  float invq[8];
  #pragma unroll
  for (int m = 0; m < 2; ++m)
    #pragma unroll
    for (int j = 0; j < 4; ++j)
      invq[m * 4 + j] = inv_q[row0 + wid * 32 + m * 16 + g * 4 + j];

  float rs[8];
  #pragma unroll
  for (int k = 0; k < 8; ++k) rs[k] = 0.0f;

  __syncthreads();   // tile 0 resident

  // 2-phase pipeline (T3 minimum): issue stage(t+1) BEFORE compute(t);
  // the single __syncthreads per tile drains vmcnt AFTER compute, so the
  // in-flight loads hide under the MFMA phase. Manual x2 unroll keeps the
  // double-buffer indices compile-time constant.
  for (int t = 0; t < NTILES; t += 2) {
    if (t + 1 < NTILES)
      stage_tile(&Bl[1][0], rbf, col00 + (t + 1) * BCOLS, wid, lane);
    compute_tile(&Bl[0][0], inv_r, col00 + t * BCOLS, av, invq, rs, g, c);
    __syncthreads();

    if (t + 2 < NTILES)
      stage_tile(&Bl[0][0], rbf, col00 + (t + 2) * BCOLS, wid, lane);
    compute_tile(&Bl[1][0], inv_r, col00 + (t + 1) * BCOLS, av, invq, rs, g, c);
    __syncthreads();
  }

  // reduce the 16 column-lanes holding the same row, one atomic per row
  #pragma unroll
  for (int k = 0; k < 8; ++k) {
    float v = rs[k];
    v += __shfl_xor(v, 1);
    v += __shfl_xor(v, 2);
    v += __shfl_xor(v, 4);
    v += __shfl_xor(v, 8);
    if (c == 0) {
      int row = row0 + wid * 32 + (k >> 2) * 16 + g * 4 + (k & 3);
      atomicAdd(&row_sum[row], v);
    }
  }
}

__global__ __launch_bounds__(256) void finalize_kernel(
    const float* __restrict__ row_sum, const float* __restrict__ pos,
    float* __restrict__ out, int n) {
  int t = threadIdx.x;
  float s = 0.f;
  #pragma unroll 4
  for (int i = t; i < n; i += 256) s += __logf(row_sum[i]) - pos[i];
  #pragma unroll
  for (int m = 1; m < 64; m <<= 1) s += __shfl_xor(s, m);
  __shared__ float red[4];
  if ((t & 63) == 0) red[t >> 6] = s;
  __syncthreads();
  if (t == 0) out[0] = red[0] + red[1] + red[2] + red[3];  // -loss = sum(lse - pos)
}

extern "C" void kernel_launch(void* const* d_in, const int* in_sizes, int n_in,
                              void* d_out, int out_size, void* d_ws, size_t ws_size,
                              hipStream_t stream) {
  const float* q = (const float*)d_in[0];
  const float* r = (const float*)d_in[1];
  int n = in_sizes[0] / DDIM;  // 8192

  char* w = (char*)d_ws;
  size_t bfBytes = (size_t)n * DDIM * 2;
  unsigned short* qbf = (unsigned short*)w;
  unsigned short* rbf = (unsigned short*)(w + bfBytes);
  float* inv_q   = (float*)(w + 2 * bfBytes);
  float* inv_r   = inv_q + n;
  float* pos     = inv_r + n;
  float* row_sum = pos + n;

  prep_kernel<<<n / 4, 256, 0, stream>>>(q, r, qbf, rbf, inv_q, inv_r, pos, row_sum);

  dim3 grid(n / BROWS, n / (NTILES * BCOLS));   // 64 x 16 = 1024 blocks
  gemm_lse_kernel<<<grid, 256, 0, stream>>>(qbf, rbf, inv_q, inv_r, row_sum);

  finalize_kernel<<<1, 256, 0, stream>>>(row_sum, pos, (float*)d_out, n);
}